// Round 4
// baseline (1155.266 us; speedup 1.0000x reference)
//
#include <hip/hip_runtime.h>

#define Bn 32
#define Tn 512
#define Dn 512
#define Vn 512

typedef _Float16 h1;
typedef _Float16 h2 __attribute__((ext_vector_type(2)));
typedef _Float16 h8 __attribute__((ext_vector_type(8)));
typedef float f4 __attribute__((ext_vector_type(4)));

__device__ __forceinline__ float max8lds(const float* p) {
  float4 a = *(const float4*)p;
  float4 b = *(const float4*)(p + 4);
  return fmaxf(fmaxf(fmaxf(a.x, a.y), fmaxf(a.z, a.w)),
               fmaxf(fmaxf(b.x, b.y), fmaxf(b.z, b.w)));
}

__device__ __forceinline__ float wavemax(float r) {
#pragma unroll
  for (int off = 1; off < 64; off <<= 1) r = fmaxf(r, __shfl_xor(r, off));
  return r;
}

// ---- global max-min of transitions (rigorous pruning radius) ----
__global__ __launch_bounds__(1024) void crf_minmax(const float* __restrict__ trans,
                                                   float* __restrict__ Rout) {
  int tid = threadIdx.x;
  float mn = 3e38f, mx = -3e38f;
  for (int i = tid; i < Vn * Vn; i += 1024) {
    float v = trans[i];
    mn = fminf(mn, v); mx = fmaxf(mx, v);
  }
#pragma unroll
  for (int off = 1; off < 64; off <<= 1) {
    mn = fminf(mn, __shfl_xor(mn, off));
    mx = fmaxf(mx, __shfl_xor(mx, off));
  }
  __shared__ float smn[16], smx[16];
  int w = tid >> 6;
  if ((tid & 63) == 0) { smn[w] = mn; smx[w] = mx; }
  __syncthreads();
  if (tid == 0) {
    for (int i = 1; i < 16; ++i) { mn = fminf(mn, smn[i]); mx = fmaxf(mx, smx[i]); }
    Rout[0] = mx - mn;
  }
}

// ---- E4: exp(trans) arranged as MFMA A-fragments ----
// frag element (vt, kc, lane, j) = exp(trans[u][v]),
//   u = kc*32 + 8*(lane>>4) + j,  v = vt*16 + (lane&15)
// stored at E4[((vt*16 + kc)*64 + lane)*8 + j]  (h1)
__global__ __launch_bounds__(256) void crf_build_E4(const float* __restrict__ trans,
                                                    h1* __restrict__ E4) {
  __shared__ float tl[32][17];
  const int vt = (int)blockIdx.x >> 4, kc = (int)blockIdx.x & 15;
  const int tid = threadIdx.x;
#pragma unroll
  for (int rep = 0; rep < 2; ++rep) {
    int l = tid + rep * 256;
    int ul = l >> 4, vl = l & 15;
    tl[ul][vl] = trans[(size_t)(kc * 32 + ul) * Vn + (vt * 16 + vl)];
  }
  __syncthreads();
  const int lane = tid & 63, jp = tid >> 6;
  const int g = lane >> 4, c = lane & 15;
#pragma unroll
  for (int j2 = 0; j2 < 2; ++j2) {
    int j = jp * 2 + j2;
    float e = __expf(tl[8 * g + j][c]);
    E4[((size_t)(vt * 16 + kc) * 64 + lane) * 8 + j] = (h1)e;
  }
}

// ---- emissions = X(16384x512) * W^T(512x512), f32, 64x64 tile BK=16 ----
__global__ __launch_bounds__(256) void crf_gemm(const float* __restrict__ X,
                                                const float* __restrict__ Wt,
                                                float* __restrict__ C) {
  __shared__ float As[16][68];
  __shared__ float Bs[16][68];
  const int tid = threadIdx.x;
  const int m0 = (int)(blockIdx.x >> 3) * 64;
  const int v0 = (int)(blockIdx.x & 7) * 64;
  const int lr = tid >> 2;
  const int lk = (tid & 3) * 4;
  const int ty = tid >> 4, tx = tid & 15;
  float acc[4][4] = {};
  const float* xrow = X + (size_t)(m0 + lr) * Dn + lk;
  const float* wrow = Wt + (size_t)(v0 + lr) * Dn + lk;
  for (int k0 = 0; k0 < Dn; k0 += 16) {
    float4 av = *(const float4*)(xrow + k0);
    float4 bv = *(const float4*)(wrow + k0);
    __syncthreads();
    As[lk + 0][lr] = av.x; As[lk + 1][lr] = av.y; As[lk + 2][lr] = av.z; As[lk + 3][lr] = av.w;
    Bs[lk + 0][lr] = bv.x; Bs[lk + 1][lr] = bv.y; Bs[lk + 2][lr] = bv.z; Bs[lk + 3][lr] = bv.w;
    __syncthreads();
#pragma unroll
    for (int kk = 0; kk < 16; ++kk) {
      float4 a = *(const float4*)&As[kk][ty * 4];
      float4 b4 = *(const float4*)&Bs[kk][tx * 4];
      float a_[4] = {a.x, a.y, a.z, a.w};
      float b_[4] = {b4.x, b4.y, b4.z, b4.w};
#pragma unroll
      for (int j = 0; j < 4; ++j)
#pragma unroll
        for (int i = 0; i < 4; ++i)
          acc[j][i] = fmaf(a_[j], b_[i], acc[j][i]);
    }
  }
#pragma unroll
  for (int j = 0; j < 4; ++j) {
    float4 o; o.x = acc[j][0]; o.y = acc[j][1]; o.z = acc[j][2]; o.w = acc[j][3];
    *(float4*)(C + (size_t)(m0 + ty * 4 + j) * Vn + v0 + tx * 4) = o;
  }
}

// ---- shared-memory union: forward vs viterbi roles ----
union SM {
  struct {
    __align__(16) uint4 ldsA[8 * 4 * 4 * 64];  // 128 KB: kc 12..15 A-frags
    __align__(16) h1 ph[Vn];                   // p broadcast (f16)
    __align__(16) float wred[8];
    __align__(16) float wred2[8];
    __align__(16) float lds_nv[Vn];
    unsigned char padsh[Tn];
  } f;
  struct {
    __align__(16) float va2[2][Vn];
    __align__(16) unsigned short bpbuf[32][Vn];
    unsigned short tokens[Tn];
    unsigned long long m8[8];
    __align__(16) float wvals[8];
    int widxs[8];
    unsigned char padsh[Tn];
    int lastS;
  } v;
};

// ---- fused scan: blocks 0..31 forward(logZ,loglik); 32..63 viterbi+backtrace ----
__global__ __launch_bounds__(512, 2) void crf_scan(
    const float* __restrict__ emis, const float* __restrict__ trans,
    const h1* __restrict__ E4, const float* __restrict__ Rp,
    const int* __restrict__ tgt, const unsigned char* __restrict__ pad,
    unsigned short* __restrict__ bps, float* __restrict__ out_ll,
    float* __restrict__ out_tok) {
  __shared__ SM sm;

  const int tid = threadIdx.x;
  const int b = blockIdx.x & 31;
  const int role = blockIdx.x >> 5;
  const float* eb = emis + (size_t)b * Tn * Vn;
  const int w = tid >> 6;
  const int lane = tid & 63;

  if (role == 0) {
    // ================== FORWARD (logsumexp via MFMA) ==================
    const int g = lane >> 4, c = lane & 15;
    const h8* E4v = (const h8*)E4;
    h8 EA[4][12];
#pragma unroll
    for (int vt2 = 0; vt2 < 4; ++vt2)
#pragma unroll
      for (int kc = 0; kc < 12; ++kc)
        EA[vt2][kc] = E4v[(size_t)((4 * w + vt2) * 16 + kc) * 64 + lane];
    // LDS-resident kc 12..15
    {
      const uint4* E4u = (const uint4*)E4;
#pragma unroll
      for (int vt2 = 0; vt2 < 4; ++vt2)
#pragma unroll
        for (int k2 = 0; k2 < 4; ++k2)
          sm.f.ldsA[(((w * 4 + vt2) * 4) + k2) * 64 + lane] =
              E4u[(size_t)((4 * w + vt2) * 16 + (12 + k2)) * 64 + lane];
    }
    sm.f.padsh[tid] = pad[b * Tn + tid];
    float alphaR = eb[tid];
    float ecur = eb[Vn + tid];
    {
      float r = wavemax(alphaR);
      if (lane == 0) sm.f.wred[w] = r;
    }
    __syncthreads();
    float m = max8lds(sm.f.wred);

    for (int t = 1; t < Tn; ++t) {
      float p = __expf(alphaR - m);
      sm.f.ph[tid] = (h1)p;
      __syncthreads();  // A: p visible to all
      float enext = (t + 1 < Tn) ? eb[(size_t)(t + 1) * Vn + tid] : 0.f;
      f4 acc0 = (f4)(0.f), acc1 = (f4)(0.f), acc2 = (f4)(0.f), acc3 = (f4)(0.f);
      const h8* phf = (const h8*)sm.f.ph;
#pragma unroll
      for (int kc = 0; kc < 12; ++kc) {
        h8 pb = phf[kc * 4 + g];
        acc0 = __builtin_amdgcn_mfma_f32_16x16x32_f16(EA[0][kc], pb, acc0, 0, 0, 0);
        acc1 = __builtin_amdgcn_mfma_f32_16x16x32_f16(EA[1][kc], pb, acc1, 0, 0, 0);
        acc2 = __builtin_amdgcn_mfma_f32_16x16x32_f16(EA[2][kc], pb, acc2, 0, 0, 0);
        acc3 = __builtin_amdgcn_mfma_f32_16x16x32_f16(EA[3][kc], pb, acc3, 0, 0, 0);
      }
#pragma unroll
      for (int k2 = 0; k2 < 4; ++k2) {
        h8 pb = phf[(12 + k2) * 4 + g];
        h8 a0 = *(const h8*)&sm.f.ldsA[(((w * 4 + 0) * 4) + k2) * 64 + lane];
        h8 a1 = *(const h8*)&sm.f.ldsA[(((w * 4 + 1) * 4) + k2) * 64 + lane];
        h8 a2 = *(const h8*)&sm.f.ldsA[(((w * 4 + 2) * 4) + k2) * 64 + lane];
        h8 a3 = *(const h8*)&sm.f.ldsA[(((w * 4 + 3) * 4) + k2) * 64 + lane];
        acc0 = __builtin_amdgcn_mfma_f32_16x16x32_f16(a0, pb, acc0, 0, 0, 0);
        acc1 = __builtin_amdgcn_mfma_f32_16x16x32_f16(a1, pb, acc1, 0, 0, 0);
        acc2 = __builtin_amdgcn_mfma_f32_16x16x32_f16(a2, pb, acc2, 0, 0, 0);
        acc3 = __builtin_amdgcn_mfma_f32_16x16x32_f16(a3, pb, acc3, 0, 0, 0);
      }
      // extract: lane (g,c) holds D[4g+r][c] of tile vt'; writes (vt'=c>>2, r=c&3)
      int r2 = c & 3, t2 = c >> 2;
      f4 at = (t2 == 0) ? acc0 : (t2 == 1) ? acc1 : (t2 == 2) ? acc2 : acc3;
      float lo = (r2 & 1) ? at[1] : at[0];
      float hi = (r2 & 1) ? at[3] : at[2];
      float tot = (r2 & 2) ? hi : lo;
      sm.f.lds_nv[w * 64 + 16 * t2 + 4 * g + r2] = tot;
      asm volatile("s_waitcnt lgkmcnt(0)" ::: "memory");
      float tv = sm.f.lds_nv[tid];
      float nv = m + __logf(tv) + ecur;
      if (sm.f.padsh[t]) nv = alphaR;
      alphaR = nv; ecur = enext;
      float rmx = wavemax(nv);
      if (lane == 0) sm.f.wred[w] = rmx;
      __syncthreads();  // B: wred visible
      m = max8lds(sm.f.wred);
    }

    // logZ + gold score
    float ex = __expf(alphaR - m);
#pragma unroll
    for (int off = 1; off < 64; off <<= 1) ex += __shfl_xor(ex, off);
    if (lane == 0) sm.f.wred[w] = ex;
    float sc;
    {
      int t = tid;
      int tg = tgt[b * Tn + t];
      float mt = sm.f.padsh[t] ? 0.f : 1.f;
      sc = eb[(size_t)t * Vn + tg] * mt;
      if (t < Tn - 1) {
        int tg1 = tgt[b * Tn + t + 1];
        float mt1 = sm.f.padsh[t + 1] ? 0.f : 1.f;
        sc += trans[(size_t)tg * Vn + tg1] * mt * mt1;
      }
    }
#pragma unroll
    for (int off = 1; off < 64; off <<= 1) sc += __shfl_xor(sc, off);
    if (lane == 0) sm.f.wred2[w] = sc;
    __syncthreads();
    if (tid == 0) {
      float s = 0.f, gg = 0.f;
      for (int i = 0; i < 8; ++i) { s += sm.f.wred[i]; gg += sm.f.wred2[i]; }
      out_ll[b] = gg - (m + __logf(s));
    }
  } else {
    // ================== VITERBI ==================
    float R = Rp[0] * 1.000001f + 1e-4f;
    sm.v.padsh[tid] = pad[b * Tn + tid];
    float vaR = eb[tid];
    sm.v.va2[0][tid] = vaR;
    float ecur = eb[Vn + tid];
    {
      float r = wavemax(vaR);
      if (lane == 0) sm.v.wvals[w] = r;
    }
    __syncthreads();
    float thr = max8lds(sm.v.wvals) - R;

    for (int t = 1; t < Tn; ++t) {
      const int cur = t & 1, prev = cur ^ 1;
      unsigned long long mk = __ballot(vaR >= thr);
      if (lane == 0) sm.v.m8[w] = mk;
      __syncthreads();  // A
      float enext = (t + 1 < Tn) ? eb[(size_t)(t + 1) * Vn + tid] : 0.f;
      float best = -3e38f; int arg = 0;
      for (int w2 = 0; w2 < 8; ++w2) {
        unsigned long long mask = sm.v.m8[w2];
        while (mask) {
          int bb = __ffsll(mask) - 1;
          int u = (w2 << 6) + bb;
          float val = sm.v.va2[prev][u] + trans[(size_t)u * Vn + tid];
          if (val > best) { best = val; arg = u; }
          mask &= mask - 1;
        }
      }
      float nv = best + ecur; int bp = arg;
      if (sm.v.padsh[t]) { nv = vaR; bp = tid; }
      bps[((size_t)(t - 1) * Bn + b) * Vn + tid] = (unsigned short)bp;
      sm.v.va2[cur][tid] = nv;
      float r2 = wavemax(nv);
      if (lane == 0) sm.v.wvals[w] = r2;
      ecur = enext; vaR = nv;
      __syncthreads();  // B
      thr = max8lds(sm.v.wvals) - R;
    }

    // last = first-index argmax of final va
    {
      float val = vaR;
      int idx = tid;
#pragma unroll
      for (int off = 1; off < 64; off <<= 1) {
        float ov = __shfl_xor(val, off);
        int oi = __shfl_xor(idx, off);
        if (ov > val || (ov == val && oi < idx)) { val = ov; idx = oi; }
      }
      if (lane == 0) { sm.v.wvals[w] = val; sm.v.widxs[w] = idx; }
    }
    __syncthreads();
    if (tid == 0) {
      float bv = sm.v.wvals[0]; int bi = sm.v.widxs[0];
      for (int i = 1; i < 8; ++i)
        if (sm.v.wvals[i] > bv || (sm.v.wvals[i] == bv && sm.v.widxs[i] < bi)) {
          bv = sm.v.wvals[i]; bi = sm.v.widxs[i];
        }
      sm.v.lastS = bi;
    }
    __syncthreads();
    int tok = sm.v.lastS;

    // backtrace: rows 510..0, 32-row LDS chunks
    for (int cch = 15; cch >= 0; --cch) {
      int rhi = cch * 32 + 31; if (rhi > 510) rhi = 510;
      int srow = tid >> 4, part = tid & 15;
      int row = cch * 32 + srow;
      if (row <= 510) {
        const uint4* src = (const uint4*)(bps + ((size_t)row * Bn + b) * Vn);
        uint4* dst = (uint4*)&sm.v.bpbuf[srow][0];
#pragma unroll
        for (int q = 0; q < 4; ++q) dst[part * 4 + q] = src[part * 4 + q];
      }
      __syncthreads();
      if (tid == 0) {
        int tk = tok;
        for (int rr = rhi; rr >= cch * 32; --rr) {
          sm.v.tokens[rr + 1] = (unsigned short)tk;
          tk = sm.v.bpbuf[rr - cch * 32][tk];
        }
        tok = tk;
      }
      __syncthreads();
    }
    if (tid == 0) sm.v.tokens[0] = (unsigned short)tok;
    __syncthreads();
    out_tok[b * Tn + tid] = (float)sm.v.tokens[tid];
  }
}

extern "C" void kernel_launch(void* const* d_in, const int* in_sizes, int n_in,
                              void* d_out, int out_size, void* d_ws, size_t ws_size,
                              hipStream_t stream) {
  const float* x = (const float*)d_in[0];
  const float* w = (const float*)d_in[1];
  const float* trans = (const float*)d_in[2];
  const int* tgt = (const int*)d_in[3];
  const unsigned char* pad = (const unsigned char*)d_in[4];
  float* out = (float*)d_out;

  char* ws = (char*)d_ws;
  float* Rp = (float*)ws;                                    // 64 B
  h1* E4 = (h1*)(ws + 64);                                   // 512 KB
  unsigned short* bps = (unsigned short*)(ws + 64 + 524288); // ~16.7 MB

  float* emis = out;                 // (B,T,V)
  float* out_ll = out + 8388608;     // (B,)
  float* out_tok = out + 8388640;    // (B,T) as float

  hipLaunchKernelGGL(crf_minmax, dim3(1), dim3(1024), 0, stream, trans, Rp);
  hipLaunchKernelGGL(crf_build_E4, dim3(512), dim3(256), 0, stream, trans, E4);
  hipLaunchKernelGGL(crf_gemm, dim3(2048), dim3(256), 0, stream, x, w, emis);
  hipLaunchKernelGGL(crf_scan, dim3(64), dim3(512), 0, stream, emis, trans, E4, Rp,
                     tgt, pad, bps, out_ll, out_tok);
}

// Round 5
// 1081.699 us; speedup vs baseline: 1.0680x; 1.0680x over previous
//
#include <hip/hip_runtime.h>

#define Bn 32
#define Tn 512
#define Dn 512
#define Vn 512

typedef _Float16 h1;
typedef _Float16 h8 __attribute__((ext_vector_type(8)));
typedef float f4 __attribute__((ext_vector_type(4)));

__device__ __forceinline__ float max8lds(const float* p) {
  float4 a = *(const float4*)p;
  float4 b = *(const float4*)(p + 4);
  return fmaxf(fmaxf(fmaxf(a.x, a.y), fmaxf(a.z, a.w)),
               fmaxf(fmaxf(b.x, b.y), fmaxf(b.z, b.w)));
}

__device__ __forceinline__ float wavemax(float r) {
#pragma unroll
  for (int off = 1; off < 64; off <<= 1) r = fmaxf(r, __shfl_xor(r, off));
  return r;
}

// raw barrier: LDS-visibility only (no vmcnt drain -> global ops float across steps)
__device__ __forceinline__ void bar_lgkm() {
  asm volatile("s_waitcnt lgkmcnt(0)" ::: "memory");
  __builtin_amdgcn_s_barrier();
}

// ---- pruning radius: max over columns v of (max_u T[u][v] - min_u T[u][v]) ----
__global__ __launch_bounds__(512) void crf_minmax(const float* __restrict__ trans,
                                                  float* __restrict__ Rout) {
  int v = threadIdx.x;
  float mn = 3e38f, mx = -3e38f;
  for (int u = 0; u < Vn; ++u) {
    float t = trans[(size_t)u * Vn + v];
    mn = fminf(mn, t); mx = fmaxf(mx, t);
  }
  float r = wavemax(mx - mn);
  __shared__ float s8[8];
  if ((threadIdx.x & 63) == 0) s8[threadIdx.x >> 6] = r;
  __syncthreads();
  if (threadIdx.x == 0) {
    float m = s8[0];
    for (int i = 1; i < 8; ++i) m = fmaxf(m, s8[i]);
    Rout[0] = m;
  }
}

// ---- E4: exp(trans) arranged as MFMA A-fragments ----
// frag element (vt, kc, lane, j) = exp(trans[u][v]),
//   u = kc*32 + 8*(lane>>4) + j,  v = vt*16 + (lane&15)
// stored at E4[((vt*16 + kc)*64 + lane)*8 + j]  (h1)
__global__ __launch_bounds__(256) void crf_build_E4(const float* __restrict__ trans,
                                                    h1* __restrict__ E4) {
  __shared__ float tl[32][17];
  const int vt = (int)blockIdx.x >> 4, kc = (int)blockIdx.x & 15;
  const int tid = threadIdx.x;
#pragma unroll
  for (int rep = 0; rep < 2; ++rep) {
    int l = tid + rep * 256;
    int ul = l >> 4, vl = l & 15;
    tl[ul][vl] = trans[(size_t)(kc * 32 + ul) * Vn + (vt * 16 + vl)];
  }
  __syncthreads();
  const int lane = tid & 63, jp = tid >> 6;
  const int g = lane >> 4, c = lane & 15;
#pragma unroll
  for (int j2 = 0; j2 < 2; ++j2) {
    int j = jp * 2 + j2;
    float e = __expf(tl[8 * g + j][c]);
    E4[((size_t)(vt * 16 + kc) * 64 + lane) * 8 + j] = (h1)e;
  }
}

// ---- emissions = X(16384x512) * W^T(512x512), f32, 64x64 tile BK=16 ----
__global__ __launch_bounds__(256) void crf_gemm(const float* __restrict__ X,
                                                const float* __restrict__ Wt,
                                                float* __restrict__ C) {
  __shared__ float As[16][68];
  __shared__ float Bs[16][68];
  const int tid = threadIdx.x;
  const int m0 = (int)(blockIdx.x >> 3) * 64;
  const int v0 = (int)(blockIdx.x & 7) * 64;
  const int lr = tid >> 2;
  const int lk = (tid & 3) * 4;
  const int ty = tid >> 4, tx = tid & 15;
  float acc[4][4] = {};
  const float* xrow = X + (size_t)(m0 + lr) * Dn + lk;
  const float* wrow = Wt + (size_t)(v0 + lr) * Dn + lk;
  for (int k0 = 0; k0 < Dn; k0 += 16) {
    float4 av = *(const float4*)(xrow + k0);
    float4 bv = *(const float4*)(wrow + k0);
    __syncthreads();
    As[lk + 0][lr] = av.x; As[lk + 1][lr] = av.y; As[lk + 2][lr] = av.z; As[lk + 3][lr] = av.w;
    Bs[lk + 0][lr] = bv.x; Bs[lk + 1][lr] = bv.y; Bs[lk + 2][lr] = bv.z; Bs[lk + 3][lr] = bv.w;
    __syncthreads();
#pragma unroll
    for (int kk = 0; kk < 16; ++kk) {
      float4 a = *(const float4*)&As[kk][ty * 4];
      float4 b4 = *(const float4*)&Bs[kk][tx * 4];
      float a_[4] = {a.x, a.y, a.z, a.w};
      float b_[4] = {b4.x, b4.y, b4.z, b4.w};
#pragma unroll
      for (int j = 0; j < 4; ++j)
#pragma unroll
        for (int i = 0; i < 4; ++i)
          acc[j][i] = fmaf(a_[j], b_[i], acc[j][i]);
    }
  }
#pragma unroll
  for (int j = 0; j < 4; ++j) {
    float4 o; o.x = acc[j][0]; o.y = acc[j][1]; o.z = acc[j][2]; o.w = acc[j][3];
    *(float4*)(C + (size_t)(m0 + ty * 4 + j) * Vn + v0 + tx * 4) = o;
  }
}

// ---- shared-memory union: forward vs viterbi roles ----
union SM {
  struct {
    __align__(16) uint4 ldsA[8 * 4 * 4 * 64];  // 128 KB: kc 12..15 A-frags
    __align__(16) h1 ph[2][Vn];                // parity-double-buffered p
    __align__(16) float wred[2][8];            // parity-double-buffered wave maxes
    __align__(16) float wred2[8];
    __align__(16) float lds_nv[Vn];
    unsigned char padsh[Tn];
  } f;
  struct {
    __align__(16) float va2[2][Vn];
    __align__(16) unsigned short bpbuf[32][Vn];
    unsigned short tokens[Tn];
    __align__(16) unsigned long long m8[8];
    __align__(16) float wvals[8];
    int widxs[8];
    unsigned char padsh[Tn];
    int lastS;
  } v;
};

// ---- fused scan: blocks 0..31 forward(logZ,loglik); 32..63 viterbi+backtrace ----
__global__ __launch_bounds__(512, 2) void crf_scan(
    const float* __restrict__ emis, const float* __restrict__ trans,
    const h1* __restrict__ E4, const float* __restrict__ Rp,
    const int* __restrict__ tgt, const unsigned char* __restrict__ pad,
    unsigned short* __restrict__ bps, float* __restrict__ out_ll,
    float* __restrict__ out_tok) {
  __shared__ SM sm;

  const int tid = threadIdx.x;
  const int b = blockIdx.x & 31;
  const int role = blockIdx.x >> 5;
  const float* eb = emis + (size_t)b * Tn * Vn;
  const int w = tid >> 6;
  const int lane = tid & 63;

  if (role == 0) {
    // ================== FORWARD (logsumexp via MFMA, 1 barrier/step) ==================
    const int g = lane >> 4, c = lane & 15;
    const h8* E4v = (const h8*)E4;
    h8 EA[4][12];
#pragma unroll
    for (int vt2 = 0; vt2 < 4; ++vt2)
#pragma unroll
      for (int kc = 0; kc < 12; ++kc)
        EA[vt2][kc] = E4v[(size_t)((4 * w + vt2) * 16 + kc) * 64 + lane];
    {
      const uint4* E4u = (const uint4*)E4;
#pragma unroll
      for (int vt2 = 0; vt2 < 4; ++vt2)
#pragma unroll
        for (int k2 = 0; k2 < 4; ++k2)
          sm.f.ldsA[(((w * 4 + vt2) * 4) + k2) * 64 + lane] =
              E4u[(size_t)((4 * w + vt2) * 16 + (12 + k2)) * 64 + lane];
    }
    sm.f.padsh[tid] = pad[b * Tn + tid];
    float alphaR = eb[tid];
    float ecur = eb[Vn + tid];
    {
      float r = wavemax(alphaR);
      if (lane == 0) sm.f.wred[0][w] = r;
    }
    bar_lgkm();
    float m_used = max8lds(sm.f.wred[0]);  // exact max(alpha_0)

    for (int t = 1; t < Tn; ++t) {
      const int q = t & 1;
      // p uses m_used = max(alpha_{t-2}) (stale by <= 1 step of growth; clamped)
      float p = __expf(fminf(alphaR - m_used, 11.0f));
      sm.f.ph[q][tid] = (h1)p;
      bar_lgkm();  // single barrier: ph[q] AND wred[q^1] (written end of t-1) visible
      float m_next = max8lds(sm.f.wred[q ^ 1]);  // exact max(alpha_{t-1})
      float enext = (t + 1 < Tn) ? eb[(size_t)(t + 1) * Vn + tid] : 0.f;
      f4 acc0 = (f4)(0.f), acc1 = (f4)(0.f), acc2 = (f4)(0.f), acc3 = (f4)(0.f);
      const h8* phf = (const h8*)sm.f.ph[q];
#pragma unroll
      for (int kc = 0; kc < 12; ++kc) {
        h8 pb = phf[kc * 4 + g];
        acc0 = __builtin_amdgcn_mfma_f32_16x16x32_f16(EA[0][kc], pb, acc0, 0, 0, 0);
        acc1 = __builtin_amdgcn_mfma_f32_16x16x32_f16(EA[1][kc], pb, acc1, 0, 0, 0);
        acc2 = __builtin_amdgcn_mfma_f32_16x16x32_f16(EA[2][kc], pb, acc2, 0, 0, 0);
        acc3 = __builtin_amdgcn_mfma_f32_16x16x32_f16(EA[3][kc], pb, acc3, 0, 0, 0);
      }
#pragma unroll
      for (int k2 = 0; k2 < 4; ++k2) {
        h8 pb = phf[(12 + k2) * 4 + g];
        h8 a0 = *(const h8*)&sm.f.ldsA[(((w * 4 + 0) * 4) + k2) * 64 + lane];
        h8 a1 = *(const h8*)&sm.f.ldsA[(((w * 4 + 1) * 4) + k2) * 64 + lane];
        h8 a2 = *(const h8*)&sm.f.ldsA[(((w * 4 + 2) * 4) + k2) * 64 + lane];
        h8 a3 = *(const h8*)&sm.f.ldsA[(((w * 4 + 3) * 4) + k2) * 64 + lane];
        acc0 = __builtin_amdgcn_mfma_f32_16x16x32_f16(a0, pb, acc0, 0, 0, 0);
        acc1 = __builtin_amdgcn_mfma_f32_16x16x32_f16(a1, pb, acc1, 0, 0, 0);
        acc2 = __builtin_amdgcn_mfma_f32_16x16x32_f16(a2, pb, acc2, 0, 0, 0);
        acc3 = __builtin_amdgcn_mfma_f32_16x16x32_f16(a3, pb, acc3, 0, 0, 0);
      }
      // extract: lane (g,c) holds D[4g+r][c] of tile vt'; writes (vt'=c>>2, r=c&3)
      int r2 = c & 3, t2 = c >> 2;
      f4 at = (t2 == 0) ? acc0 : (t2 == 1) ? acc1 : (t2 == 2) ? acc2 : acc3;
      float lo = (r2 & 1) ? at[1] : at[0];
      float hi = (r2 & 1) ? at[3] : at[2];
      float tot = (r2 & 2) ? hi : lo;
      sm.f.lds_nv[w * 64 + 16 * t2 + 4 * g + r2] = tot;
      asm volatile("s_waitcnt lgkmcnt(0)" ::: "memory");
      float tv = sm.f.lds_nv[tid];
      float nv = m_used + __logf(tv) + ecur;
      if (sm.f.padsh[t]) nv = alphaR;
      alphaR = nv; ecur = enext;
      float rmx = wavemax(nv);
      if (lane == 0) sm.f.wred[q][w] = rmx;  // visible after next iter's barrier
      m_used = m_next;
    }

    // epilogue: logZ + gold score (one-time full syncs are fine)
    __syncthreads();
    float m = max8lds(sm.f.wred[1]);  // t=511 wrote q=1: exact max(alpha_511)
    float ex = __expf(alphaR - m);
#pragma unroll
    for (int off = 1; off < 64; off <<= 1) ex += __shfl_xor(ex, off);
    if (lane == 0) sm.f.wred[0][w] = ex;
    float sc;
    {
      int t = tid;
      int tg = tgt[b * Tn + t];
      float mt = sm.f.padsh[t] ? 0.f : 1.f;
      sc = eb[(size_t)t * Vn + tg] * mt;
      if (t < Tn - 1) {
        int tg1 = tgt[b * Tn + t + 1];
        float mt1 = sm.f.padsh[t + 1] ? 0.f : 1.f;
        sc += trans[(size_t)tg * Vn + tg1] * mt * mt1;
      }
    }
#pragma unroll
    for (int off = 1; off < 64; off <<= 1) sc += __shfl_xor(sc, off);
    if (lane == 0) sm.f.wred2[w] = sc;
    __syncthreads();
    if (tid == 0) {
      float s = 0.f, gg = 0.f;
      for (int i = 0; i < 8; ++i) { s += sm.f.wred[0][i]; gg += sm.f.wred2[i]; }
      out_ll[b] = gg - (m + __logf(s));
    }
  } else {
    // ================== VITERBI (raw barriers, pipelined candidate loads) ==================
    float R = Rp[0] * 1.000001f + 1e-4f;
    sm.v.padsh[tid] = pad[b * Tn + tid];
    float vaR = eb[tid];
    sm.v.va2[0][tid] = vaR;
    float ecur = eb[Vn + tid];
    {
      float r = wavemax(vaR);
      if (lane == 0) sm.v.wvals[w] = r;
    }
    bar_lgkm();
    float thr = max8lds(sm.v.wvals) - R;

    for (int t = 1; t < Tn; ++t) {
      const int cur = t & 1, prev = cur ^ 1;
      unsigned long long mk = __ballot(vaR >= thr);
      if (lane == 0) sm.v.m8[w] = mk;
      bar_lgkm();  // A: m8 + va2[prev] visible
      float enext = (t + 1 < Tn) ? eb[(size_t)(t + 1) * Vn + tid] : 0.f;
      unsigned long long M[8];
#pragma unroll
      for (int i = 0; i < 4; ++i)
        ((ulonglong2*)M)[i] = ((const ulonglong2*)sm.v.m8)[i];
      float best = -3e38f; int arg = 0;
#pragma unroll
      for (int w2 = 0; w2 < 8; ++w2) {
        unsigned long long mask = M[w2];
        while (mask) {  // wave-uniform walk, ascending u (first-index argmax)
          int b0 = __ffsll((unsigned long long)mask) - 1; mask &= mask - 1;
          int u0 = (w2 << 6) + b0;
          float t0 = trans[(size_t)u0 * Vn + tid];
          float v0 = sm.v.va2[prev][u0];
          if (mask) {
            int b1 = __ffsll((unsigned long long)mask) - 1; mask &= mask - 1;
            int u1 = (w2 << 6) + b1;
            float t1 = trans[(size_t)u1 * Vn + tid];
            float v1 = sm.v.va2[prev][u1];
            float c0 = v0 + t0;
            if (c0 > best) { best = c0; arg = u0; }
            float c1 = v1 + t1;
            if (c1 > best) { best = c1; arg = u1; }
          } else {
            float c0 = v0 + t0;
            if (c0 > best) { best = c0; arg = u0; }
          }
        }
      }
      float nv = best + ecur; int bp = arg;
      if (sm.v.padsh[t]) { nv = vaR; bp = tid; }
      bps[((size_t)(t - 1) * Bn + b) * Vn + tid] = (unsigned short)bp;  // floats free
      sm.v.va2[cur][tid] = nv;
      float r2 = wavemax(nv);
      if (lane == 0) sm.v.wvals[w] = r2;
      bar_lgkm();  // B: wvals + va2[cur] visible
      thr = max8lds(sm.v.wvals) - R;
      ecur = enext; vaR = nv;
    }

    // drain bps stores once, then backtrace
    asm volatile("s_waitcnt vmcnt(0)" ::: "memory");
    __syncthreads();

    {
      float val = vaR;
      int idx = tid;
#pragma unroll
      for (int off = 1; off < 64; off <<= 1) {
        float ov = __shfl_xor(val, off);
        int oi = __shfl_xor(idx, off);
        if (ov > val || (ov == val && oi < idx)) { val = ov; idx = oi; }
      }
      if (lane == 0) { sm.v.wvals[w] = val; sm.v.widxs[w] = idx; }
    }
    __syncthreads();
    if (tid == 0) {
      float bv = sm.v.wvals[0]; int bi = sm.v.widxs[0];
      for (int i = 1; i < 8; ++i)
        if (sm.v.wvals[i] > bv || (sm.v.wvals[i] == bv && sm.v.widxs[i] < bi)) {
          bv = sm.v.wvals[i]; bi = sm.v.widxs[i];
        }
      sm.v.lastS = bi;
    }
    __syncthreads();
    int tok = sm.v.lastS;

    // backtrace: rows 510..0, 32-row LDS chunks
    for (int cch = 15; cch >= 0; --cch) {
      int rhi = cch * 32 + 31; if (rhi > 510) rhi = 510;
      int srow = tid >> 4, part = tid & 15;
      int row = cch * 32 + srow;
      if (row <= 510) {
        const uint4* src = (const uint4*)(bps + ((size_t)row * Bn + b) * Vn);
        uint4* dst = (uint4*)&sm.v.bpbuf[srow][0];
#pragma unroll
        for (int q = 0; q < 4; ++q) dst[part * 4 + q] = src[part * 4 + q];
      }
      __syncthreads();
      if (tid == 0) {
        int tk = tok;
        for (int rr = rhi; rr >= cch * 32; --rr) {
          sm.v.tokens[rr + 1] = (unsigned short)tk;
          tk = sm.v.bpbuf[rr - cch * 32][tk];
        }
        tok = tk;
      }
      __syncthreads();
    }
    if (tid == 0) sm.v.tokens[0] = (unsigned short)tok;
    __syncthreads();
    out_tok[b * Tn + tid] = (float)sm.v.tokens[tid];
  }
}

extern "C" void kernel_launch(void* const* d_in, const int* in_sizes, int n_in,
                              void* d_out, int out_size, void* d_ws, size_t ws_size,
                              hipStream_t stream) {
  const float* x = (const float*)d_in[0];
  const float* w = (const float*)d_in[1];
  const float* trans = (const float*)d_in[2];
  const int* tgt = (const int*)d_in[3];
  const unsigned char* pad = (const unsigned char*)d_in[4];
  float* out = (float*)d_out;

  char* ws = (char*)d_ws;
  float* Rp = (float*)ws;                                    // 64 B
  h1* E4 = (h1*)(ws + 64);                                   // 512 KB
  unsigned short* bps = (unsigned short*)(ws + 64 + 524288); // ~16.7 MB

  float* emis = out;                 // (B,T,V)
  float* out_ll = out + 8388608;     // (B,)
  float* out_tok = out + 8388640;    // (B,T) as float

  hipLaunchKernelGGL(crf_minmax, dim3(1), dim3(512), 0, stream, trans, Rp);
  hipLaunchKernelGGL(crf_build_E4, dim3(512), dim3(256), 0, stream, trans, E4);
  hipLaunchKernelGGL(crf_gemm, dim3(2048), dim3(256), 0, stream, x, w, emis);
  hipLaunchKernelGGL(crf_scan, dim3(64), dim3(512), 0, stream, emis, trans, E4, Rp,
                     tgt, pad, bps, out_ll, out_tok);
}